// Round 1
// baseline (145.617 us; speedup 1.0000x reference)
//
#include <hip/hip_runtime.h>

// FractionalDerivative: out[b,c,t] = sum_{k=0}^{K-1} w[c,k] * x[b,c,t-k]
// w_0 = 1, w_k = w_{k-1} * (k-1-a)/k, a = clip(alpha[c], 0.01, 1.99)
// x: (16, 512, 8192) fp32, alpha: (512,) fp32, out same shape as x.
// Memory-bound: 512 MiB total traffic -> target ~6 TB/s.

constexpr int K = 10;
constexpr int T = 8192;
constexpr int C = 512;

__global__ __launch_bounds__(256) void frac_deriv_kernel(
    const float* __restrict__ x,
    const float* __restrict__ alpha,
    float* __restrict__ out) {
    const int row = blockIdx.x;        // row = b*C + c, one block per row
    const int c = row & (C - 1);

    // Per-channel GL weights (block-uniform; 9 ops, hoisted out of t-loop)
    float a = alpha[c];
    a = fminf(fmaxf(a, 0.01f), 1.99f);
    float w[K];
    w[0] = 1.0f;
#pragma unroll
    for (int k = 1; k < K; ++k) {
        w[k] = w[k - 1] * ((float)k - 1.0f - a) / (float)k;
    }

    const float* xr  = x   + (size_t)row * T;
    float*       outr = out + (size_t)row * T;

    // 2048 float4 per row / 256 threads = 8 iterations
#pragma unroll
    for (int it = 0; it < T / 4 / 256; ++it) {
        const int t0 = (it * 256 + (int)threadIdx.x) * 4;

        // Window x[t0-12 .. t0+3] via 4 aligned float4 loads.
        // Blocks are uniformly valid/invalid (t0 multiple of 4): zero-fill t<0.
        float xa[16];
#pragma unroll
        for (int blk = 0; blk < 4; ++blk) {
            const int tb = t0 - 12 + blk * 4;
            float4 v;
            if (tb >= 0) {
                v = *reinterpret_cast<const float4*>(xr + tb);
            } else {
                v = make_float4(0.f, 0.f, 0.f, 0.f);
            }
            xa[blk * 4 + 0] = v.x;
            xa[blk * 4 + 1] = v.y;
            xa[blk * 4 + 2] = v.z;
            xa[blk * 4 + 3] = v.w;
        }

        float o[4];
#pragma unroll
        for (int j = 0; j < 4; ++j) {
            float acc = 0.0f;
#pragma unroll
            for (int k = 0; k < K; ++k) {
                acc = fmaf(w[k], xa[12 + j - k], acc);
            }
            o[j] = acc;
        }
        *reinterpret_cast<float4*>(outr + t0) = make_float4(o[0], o[1], o[2], o[3]);
    }
}

extern "C" void kernel_launch(void* const* d_in, const int* in_sizes, int n_in,
                              void* d_out, int out_size, void* d_ws, size_t ws_size,
                              hipStream_t stream) {
    const float* x     = (const float*)d_in[0];
    const float* alpha = (const float*)d_in[1];
    float*       out   = (float*)d_out;

    const int nrows = in_sizes[0] / T;  // B*C = 8192 rows
    frac_deriv_kernel<<<nrows, 256, 0, stream>>>(x, alpha, out);
}

// Round 2
// 144.264 us; speedup vs baseline: 1.0094x; 1.0094x over previous
//
#include <hip/hip_runtime.h>

// FractionalDerivative: out[b,c,t] = sum_{k=0}^{K-1} w[c,k] * x[b,c,t-k]
// w_0 = 1, w_k = w_{k-1} * (k-1-a)/k, a = clip(alpha[c], 0.01, 1.99)
// x: (16, 512, 8192) fp32. Memory-bound (409 MB HBM after L3) -> target ~4+ TB/s.
// R1: explicit 2-deep register pipeline (load it+1 before compute of it) to fix
// the per-iteration vmcnt(0) latency stall seen in R0 (VGPR=32, serial schedule).

constexpr int K = 10;
constexpr int T = 8192;
constexpr int C = 512;
constexpr int ITERS = T / 4 / 256;  // 8 float4-iterations per thread

__device__ __forceinline__ void load_win_guarded(const float* __restrict__ xr,
                                                 int t0, float* xa) {
#pragma unroll
    for (int blk = 0; blk < 4; ++blk) {
        const int tb = t0 - 12 + blk * 4;
        float4 v = make_float4(0.f, 0.f, 0.f, 0.f);
        if (tb >= 0) v = *reinterpret_cast<const float4*>(xr + tb);
        xa[blk * 4 + 0] = v.x;
        xa[blk * 4 + 1] = v.y;
        xa[blk * 4 + 2] = v.z;
        xa[blk * 4 + 3] = v.w;
    }
}

__device__ __forceinline__ void load_win(const float* __restrict__ xr,
                                         int t0, float* xa) {
#pragma unroll
    for (int blk = 0; blk < 4; ++blk) {
        const float4 v = *reinterpret_cast<const float4*>(xr + t0 - 12 + blk * 4);
        xa[blk * 4 + 0] = v.x;
        xa[blk * 4 + 1] = v.y;
        xa[blk * 4 + 2] = v.z;
        xa[blk * 4 + 3] = v.w;
    }
}

__device__ __forceinline__ void compute_store(const float* __restrict__ w,
                                              const float* __restrict__ xa,
                                              float* __restrict__ outr, int t0) {
    float o[4];
#pragma unroll
    for (int j = 0; j < 4; ++j) {
        float acc = 0.0f;
#pragma unroll
        for (int k = 0; k < K; ++k) {
            acc = fmaf(w[k], xa[12 + j - k], acc);
        }
        o[j] = acc;
    }
    *reinterpret_cast<float4*>(outr + t0) = make_float4(o[0], o[1], o[2], o[3]);
}

__global__ __launch_bounds__(256) void frac_deriv_kernel(
    const float* __restrict__ x,
    const float* __restrict__ alpha,
    float* __restrict__ out) {
    const int row = blockIdx.x;        // row = b*C + c, one block per row
    const int c = row & (C - 1);

    // Per-channel GL weights (block-uniform, hoisted)
    float a = alpha[c];
    a = fminf(fmaxf(a, 0.01f), 1.99f);
    float w[K];
    w[0] = 1.0f;
#pragma unroll
    for (int k = 1; k < K; ++k) {
        w[k] = w[k - 1] * ((float)k - 1.0f - a) / (float)k;
    }

    const float* xr   = x   + (size_t)row * T;
    float*       outr = out + (size_t)row * T;
    const int tid = (int)threadIdx.x;

    // Ping-pong register buffers; all indexing static after full unroll.
    float bufA[16];
    float bufB[16];

    // Prologue: iteration 0 window (only threads 0..2 hit t<0 -> guarded)
    load_win_guarded(xr, tid * 4, bufA);

#pragma unroll
    for (int it = 0; it < ITERS; ++it) {
        float* cur = (it & 1) ? bufB : bufA;
        float* nxt = (it & 1) ? bufA : bufB;
        // Issue next iteration's loads BEFORE computing current (stays in
        // flight across the counted vmcnt wait for `cur`).
        if (it + 1 < ITERS) {
            load_win(xr, ((it + 1) * 256 + tid) * 4, nxt);
        }
        compute_store(w, cur, outr, (it * 256 + tid) * 4);
    }
}

extern "C" void kernel_launch(void* const* d_in, const int* in_sizes, int n_in,
                              void* d_out, int out_size, void* d_ws, size_t ws_size,
                              hipStream_t stream) {
    const float* x     = (const float*)d_in[0];
    const float* alpha = (const float*)d_in[1];
    float*       out   = (float*)d_out;

    const int nrows = in_sizes[0] / T;  // B*C = 8192 rows
    frac_deriv_kernel<<<nrows, 256, 0, stream>>>(x, alpha, out);
}